// Round 2
// baseline (1851.933 us; speedup 1.0000x reference)
//
#include <hip/hip_runtime.h>

typedef __bf16 bf16x2 __attribute__((ext_vector_type(2)));
typedef __bf16 bf16x4 __attribute__((ext_vector_type(4)));
typedef __bf16 bf16x8 __attribute__((ext_vector_type(8)));
typedef float f32x4 __attribute__((ext_vector_type(4)));

#define LDSTR 40  // LDS row stride in bf16 elems (32 + 8 pad: keeps 16B align, 2-way-max bank aliasing)

// ---------------- CSR build ----------------
__global__ void hist_kernel(const int* __restrict__ dst, int* __restrict__ deg, int E) {
    int i = blockIdx.x * 256 + threadIdx.x;
    if (i < E) atomicAdd(&deg[dst[i]], 1);
}

__global__ __launch_bounds__(1024)
void scan_kernel(const int* __restrict__ deg, int* __restrict__ rowptr,
                 int* __restrict__ cursor, int n) {
    __shared__ int part[1024];
    int tid = threadIdx.x;
    int chunk = (n + 1023) >> 10;
    int beg = tid * chunk;
    int fin = min(beg + chunk, n);
    int s = 0;
    for (int i = beg; i < fin; i++) s += deg[i];
    part[tid] = s;
    __syncthreads();
    for (int off = 1; off < 1024; off <<= 1) {
        int v = (tid >= off) ? part[tid - off] : 0;
        __syncthreads();
        part[tid] += v;
        __syncthreads();
    }
    int run = (tid == 0) ? 0 : part[tid - 1];
    for (int i = beg; i < fin; i++) {
        rowptr[i] = run; cursor[i] = run; run += deg[i];
    }
    if (tid == 1023) rowptr[n] = run;
}

__global__ void scatter_kernel(const int* __restrict__ src, const int* __restrict__ dst,
                               int* __restrict__ cursor, int* __restrict__ colsrc, int E) {
    int i = blockIdx.x * 256 + threadIdx.x;
    if (i < E) {
        int p = atomicAdd(&cursor[dst[i]], 1);
        colsrc[p] = src[i];
    }
}

// ---------------- dtype convert / weight prep ----------------
__global__ void f32_to_bf16_kernel(const float* __restrict__ in, __bf16* __restrict__ out, int n4) {
    int i = blockIdx.x * 256 + threadIdx.x;
    if (i < n4) {
        float4 f = ((const float4*)in)[i];
        bf16x4 o;
        o[0] = (__bf16)f.x; o[1] = (__bf16)f.y; o[2] = (__bf16)f.z; o[3] = (__bf16)f.w;
        ((bf16x4*)out)[i] = o;
    }
}

// out[n*K+k] = bf16(in[k*512+n]); K = 1<<kbits (in is K x 512 row-major)
__global__ void wprep_kernel(const float* __restrict__ in, __bf16* __restrict__ out, int kbits) {
    int idx = blockIdx.x * 256 + threadIdx.x;
    int K = 1 << kbits;
    if (idx < (512 << kbits)) {
        int k = idx & (K - 1);
        int n = idx >> kbits;
        out[idx] = (__bf16)in[k * 512 + n];
    }
}

// ---------------- aggregation: h[i] = x[i] + sum_{j->i} x[j]  (wave per node) ----------------
template<int F>  // floats per lane; DIM = 64*F
__global__ __launch_bounds__(256)
void agg_kernel(const __bf16* __restrict__ xb, const int* __restrict__ rowptr,
                const int* __restrict__ colsrc, float* __restrict__ h, int n) {
    const int node = blockIdx.x * 4 + (threadIdx.x >> 6);
    if (node >= n) return;
    const int lane = threadIdx.x & 63;
    const int DIM = F * 64;
    float acc[F];
    {
        const __bf16* p = xb + (size_t)node * DIM + lane * F;
        if constexpr (F == 8) {
            bf16x8 v = *(const bf16x8*)p;
            #pragma unroll
            for (int i = 0; i < 8; i++) acc[i] = (float)v[i];
        } else {
            bf16x2 v = *(const bf16x2*)p;
            acc[0] = (float)v[0]; acc[1] = (float)v[1];
        }
    }
    int e = rowptr[node], end = rowptr[node + 1];
    for (; e + 2 <= end; e += 2) {   // unroll-2: two independent gathers in flight
        int s0 = colsrc[e], s1 = colsrc[e + 1];
        const __bf16* p0 = xb + (size_t)s0 * DIM + lane * F;
        const __bf16* p1 = xb + (size_t)s1 * DIM + lane * F;
        if constexpr (F == 8) {
            bf16x8 v0 = *(const bf16x8*)p0;
            bf16x8 v1 = *(const bf16x8*)p1;
            #pragma unroll
            for (int i = 0; i < 8; i++) acc[i] += (float)v0[i] + (float)v1[i];
        } else {
            bf16x2 v0 = *(const bf16x2*)p0;
            bf16x2 v1 = *(const bf16x2*)p1;
            acc[0] += (float)v0[0] + (float)v1[0];
            acc[1] += (float)v0[1] + (float)v1[1];
        }
    }
    if (e < end) {
        int s0 = colsrc[e];
        const __bf16* p0 = xb + (size_t)s0 * DIM + lane * F;
        if constexpr (F == 8) {
            bf16x8 v0 = *(const bf16x8*)p0;
            #pragma unroll
            for (int i = 0; i < 8; i++) acc[i] += (float)v0[i];
        } else {
            bf16x2 v0 = *(const bf16x2*)p0;
            acc[0] += (float)v0[0]; acc[1] += (float)v0[1];
        }
    }
    float* out = h + (size_t)node * DIM + lane * F;
    if constexpr (F == 8) {
        *(float4*)out       = make_float4(acc[0], acc[1], acc[2], acc[3]);
        *(float4*)(out + 4) = make_float4(acc[4], acc[5], acc[6], acc[7]);
    } else {
        *(float2*)out = make_float2(acc[0], acc[1]);
    }
}

// ---------------- MFMA GEMM: out = epilogue(A @ Bt^T + bias) ----------------
// A: fp32 (AMODE 0, M x K) or constructed edge features from bf16 node table (AMODE 1, K=1024)
// A is split hi/lo bf16 (exact), B is pre-transposed bf16 [512][K].
// 128x128 block, 4 waves (2x2), each wave 64x64 via 4x4 tiles of mfma_f32_16x16x32_bf16.
template<int AMODE, bool RELU, bool OUTBF16>
__global__ __launch_bounds__(256, 2)
void gemm_kernel(const float* __restrict__ A, const __bf16* __restrict__ Xb,
                 const int* __restrict__ cand, const __bf16* __restrict__ Bt,
                 const float* __restrict__ bias, void* __restrict__ Cout,
                 int M, int K) {
    __shared__ __bf16 sAhi[128 * LDSTR];
    __shared__ __bf16 sAlo[128 * LDSTR];
    __shared__ __bf16 sB[128 * LDSTR];

    const int tid = threadIdx.x;
    const int lane = tid & 63;
    const int wid = tid >> 6;
    const int waveM = wid & 1;
    const int waveN = wid >> 1;
    const int mlane = lane & 15;
    const int quad = lane >> 4;
    const int rowBase = blockIdx.x * 128;
    const int nBase = blockIdx.y * 128;

    const int ar = tid >> 3;        // A stage: 32 row-groups x 8 col-groups (4 floats each)
    const int ac = (tid & 7) << 2;
    const int br = tid >> 2;        // B stage: 64 row-groups x 4 col-groups (8 bf16 each)
    const int bc = (tid & 3) << 3;

    const f32x4 fzero = {0.f, 0.f, 0.f, 0.f};
    f32x4 acc[4][4];
    #pragma unroll
    for (int i = 0; i < 4; i++)
        #pragma unroll
        for (int j = 0; j < 4; j++) acc[i][j] = fzero;

    int uu[4], vv[4];
    if (AMODE == 1) {
        #pragma unroll
        for (int i = 0; i < 4; i++) {
            int grow = rowBase + ar + i * 32;
            uu[i] = 0; vv[i] = 0;
            if (grow < M) { uu[i] = cand[2 * grow]; vv[i] = cand[2 * grow + 1]; }
        }
    }

    for (int k0 = 0; k0 < K; k0 += 32) {
        __syncthreads();
        // ---- stage A (fp32 -> hi/lo bf16) ----
        #pragma unroll
        for (int i = 0; i < 4; i++) {
            int rr = ar + i * 32;
            int grow = rowBase + rr;
            float fv[4] = {0.f, 0.f, 0.f, 0.f};
            if (AMODE == 0) {
                if (grow < M) {
                    float4 f = *(const float4*)(A + (size_t)grow * K + k0 + ac);
                    fv[0] = f.x; fv[1] = f.y; fv[2] = f.z; fv[3] = f.w;
                }
            } else {
                if (grow < M) {
                    int k = k0 + ac;
                    int kk = (k < 512) ? k : (k - 512);
                    bf16x4 xu = *(const bf16x4*)(Xb + (size_t)uu[i] * 512 + kk);
                    bf16x4 xv = *(const bf16x4*)(Xb + (size_t)vv[i] * 512 + kk);
                    if (k < 512) {
                        #pragma unroll
                        for (int q = 0; q < 4; q++) fv[q] = (float)xu[q] + (float)xv[q];
                    } else {
                        #pragma unroll
                        for (int q = 0; q < 4; q++) fv[q] = fabsf((float)xu[q] - (float)xv[q]);
                    }
                }
            }
            bf16x4 hi, lo;
            #pragma unroll
            for (int q = 0; q < 4; q++) {
                __bf16 hq = (__bf16)fv[q];
                hi[q] = hq;
                lo[q] = (__bf16)(fv[q] - (float)hq);
            }
            *(bf16x4*)(sAhi + rr * LDSTR + ac) = hi;
            *(bf16x4*)(sAlo + rr * LDSTR + ac) = lo;
        }
        // ---- stage B (FIX: global row = nBase + nn) ----
        #pragma unroll
        for (int i = 0; i < 2; i++) {
            int nn = br + i * 64;
            bf16x8 b = *(const bf16x8*)(Bt + (size_t)(nBase + nn) * K + k0 + bc);
            *(bf16x8*)(sB + nn * LDSTR + bc) = b;
        }
        __syncthreads();

        // ---- fragments + MFMA ----
        bf16x8 aH[4], aL[4], bH[4];
        #pragma unroll
        for (int mt = 0; mt < 4; mt++) {
            int r = waveM * 64 + mt * 16 + mlane;
            aH[mt] = *(const bf16x8*)(sAhi + r * LDSTR + quad * 8);
            aL[mt] = *(const bf16x8*)(sAlo + r * LDSTR + quad * 8);
        }
        #pragma unroll
        for (int nt = 0; nt < 4; nt++) {
            int r = waveN * 64 + nt * 16 + mlane;
            bH[nt] = *(const bf16x8*)(sB + r * LDSTR + quad * 8);
        }
        #pragma unroll
        for (int mt = 0; mt < 4; mt++)
            #pragma unroll
            for (int nt = 0; nt < 4; nt++) {
                acc[mt][nt] = __builtin_amdgcn_mfma_f32_16x16x32_bf16(aH[mt], bH[nt], acc[mt][nt], 0, 0, 0);
                acc[mt][nt] = __builtin_amdgcn_mfma_f32_16x16x32_bf16(aL[mt], bH[nt], acc[mt][nt], 0, 0, 0);
            }
    }

    // ---- epilogue: D col=lane&15, row=quad*4+r ----
    #pragma unroll
    for (int mt = 0; mt < 4; mt++) {
        #pragma unroll
        for (int nt = 0; nt < 4; nt++) {
            int col = nBase + waveN * 64 + nt * 16 + mlane;
            float bv = bias[col];
            #pragma unroll
            for (int r = 0; r < 4; r++) {
                int row = rowBase + waveM * 64 + mt * 16 + quad * 4 + r;
                if (row < M) {
                    float v = acc[mt][nt][r] + bv;
                    if (RELU) v = fmaxf(v, 0.f);
                    if (OUTBF16) ((__bf16*)Cout)[(size_t)row * 512 + col] = (__bf16)v;
                    else ((float*)Cout)[(size_t)row * 512 + col] = v;
                }
            }
        }
    }
}

// ---------------- head constant vector ----------------
// cvec[n] = pred_b1[n] + first_feat @ pred_w1[0:1024] + t_embed @ pred_w1[2048:2560]
__global__ __launch_bounds__(512)
void constvec_kernel(const __bf16* __restrict__ xb, const int* __restrict__ first_edge,
                     const float* __restrict__ t,
                     const float* __restrict__ tw1, const float* __restrict__ tb1,
                     const float* __restrict__ tw2, const float* __restrict__ tb2,
                     const float* __restrict__ pw1, const float* __restrict__ pb1,
                     float* __restrict__ cvec) {
    __shared__ float z1[512];
    __shared__ float te[512];
    __shared__ float ff[1024];
    int tid = threadIdx.x;
    float tv = t[0];
    z1[tid] = fmaxf(tv * tw1[tid] + tb1[tid], 0.f);
    int u = first_edge[0], v = first_edge[1];
    float xu = (float)xb[(size_t)u * 512 + tid];
    float xv = (float)xb[(size_t)v * 512 + tid];
    ff[tid] = xu + xv;
    ff[512 + tid] = fabsf(xu - xv);
    __syncthreads();
    float s = tb2[tid];
    for (int j = 0; j < 512; j++) s += z1[j] * tw2[j * 512 + tid];
    te[tid] = s;
    __syncthreads();
    float c = pb1[tid];
    for (int k = 0; k < 1024; k++) c += ff[k] * pw1[k * 512 + tid];
    for (int j = 0; j < 512; j++) c += te[j] * pw1[(2048 + j) * 512 + tid];
    cvec[tid] = c;
}

// ---------------- final dot: logits[c] = Z[c,:] . w2 + b2 ----------------
__global__ __launch_bounds__(256)
void logits_kernel(const float* __restrict__ Z, const float* __restrict__ w2,
                   const float* __restrict__ b2, float* __restrict__ out, int C) {
    int c = blockIdx.x * 4 + (threadIdx.x >> 6);
    if (c >= C) return;
    int lane = threadIdx.x & 63;
    const float4* z = (const float4*)(Z + (size_t)c * 512 + lane * 8);
    const float4* w = (const float4*)(w2 + lane * 8);
    float4 z0 = z[0], z1 = z[1], w0 = w[0], w1 = w[1];
    float s = z0.x * w0.x + z0.y * w0.y + z0.z * w0.z + z0.w * w0.w
            + z1.x * w1.x + z1.y * w1.y + z1.z * w1.z + z1.w * w1.w;
    #pragma unroll
    for (int off = 32; off > 0; off >>= 1) s += __shfl_down(s, off);
    if (lane == 0) out[c] = s + b2[0];
}

extern "C" void kernel_launch(void* const* d_in, const int* in_sizes, int n_in,
                              void* d_out, int out_size, void* d_ws, size_t ws_size,
                              hipStream_t stream) {
    (void)n_in; (void)out_size; (void)ws_size;
    const float* x          = (const float*)d_in[0];
    const int*   edge_index = (const int*)d_in[1];
    const int*   first_edge = (const int*)d_in[2];
    const int*   cand       = (const int*)d_in[3];
    const float* t          = (const float*)d_in[4];
    const float* gw1[3] = {(const float*)d_in[5], (const float*)d_in[9],  (const float*)d_in[13]};
    const float* gb1[3] = {(const float*)d_in[6], (const float*)d_in[10], (const float*)d_in[14]};
    const float* gw2[3] = {(const float*)d_in[7], (const float*)d_in[11], (const float*)d_in[15]};
    const float* gb2[3] = {(const float*)d_in[8], (const float*)d_in[12], (const float*)d_in[16]};
    const float* pw1 = (const float*)d_in[17];
    const float* pb1 = (const float*)d_in[18];
    const float* pw2 = (const float*)d_in[19];
    const float* pb2 = (const float*)d_in[20];
    const float* tw1 = (const float*)d_in[21];
    const float* tb1 = (const float*)d_in[22];
    const float* tw2 = (const float*)d_in[23];
    const float* tb2 = (const float*)d_in[24];

    const int N = in_sizes[0] / 128;   // 50000
    const int E = in_sizes[1] / 2;     // 1600000
    const int C = in_sizes[3] / 2;     // 50000

    char* p = (char*)d_ws;
    auto alloc = [&](size_t bytes) -> void* {
        void* r = (void*)p;
        p += (bytes + 255) & ~(size_t)255;
        return r;
    };
    float*  h    = (float*)alloc((size_t)N * 512 * 4);
    float*  u    = (float*)alloc((size_t)N * 512 * 4);   // also: Z for head; its head holds xb0 pre-L0
    __bf16* xb   = (__bf16*)alloc((size_t)N * 512 * 2);
    __bf16* wt01 = (__bf16*)alloc((size_t)512 * 128 * 2);
    __bf16* wt02 = (__bf16*)alloc((size_t)512 * 512 * 2);
    __bf16* wt11 = (__bf16*)alloc((size_t)512 * 512 * 2);
    __bf16* wt12 = (__bf16*)alloc((size_t)512 * 512 * 2);
    __bf16* wt21 = (__bf16*)alloc((size_t)512 * 512 * 2);
    __bf16* wt22 = (__bf16*)alloc((size_t)512 * 512 * 2);
    __bf16* wtH  = (__bf16*)alloc((size_t)512 * 1024 * 2);
    int* rowptr = (int*)alloc((size_t)(N + 1) * 4);
    int* deg    = (int*)alloc((size_t)N * 4);
    int* cursor = (int*)alloc((size_t)N * 4);
    int* colsrc = (int*)alloc((size_t)E * 4);
    float* cvec = (float*)alloc(512 * 4);
    __bf16* xb0 = (__bf16*)u;   // alias: xb0 dead before u is first written (L0 gemm1)

    const int* src = edge_index;
    const int* dst = edge_index + E;

    // CSR build
    hipMemsetAsync(deg, 0, (size_t)N * 4, stream);
    int eb = (E + 255) / 256;
    hist_kernel<<<eb, 256, 0, stream>>>(dst, deg, E);
    scan_kernel<<<1, 1024, 0, stream>>>(deg, rowptr, cursor, N);
    scatter_kernel<<<eb, 256, 0, stream>>>(src, dst, cursor, colsrc, E);

    // input + weight prep
    f32_to_bf16_kernel<<<((N * 128 / 4) + 255) / 256, 256, 0, stream>>>(x, xb0, N * 128 / 4);
    wprep_kernel<<<((512 << 7)  + 255) / 256, 256, 0, stream>>>(gw1[0], wt01, 7);
    wprep_kernel<<<((512 << 9)  + 255) / 256, 256, 0, stream>>>(gw2[0], wt02, 9);
    wprep_kernel<<<((512 << 9)  + 255) / 256, 256, 0, stream>>>(gw1[1], wt11, 9);
    wprep_kernel<<<((512 << 9)  + 255) / 256, 256, 0, stream>>>(gw2[1], wt12, 9);
    wprep_kernel<<<((512 << 9)  + 255) / 256, 256, 0, stream>>>(gw1[2], wt21, 9);
    wprep_kernel<<<((512 << 9)  + 255) / 256, 256, 0, stream>>>(gw2[2], wt22, 9);
    wprep_kernel<<<((512 << 10) + 255) / 256, 256, 0, stream>>>(pw1 + (size_t)1024 * 512, wtH, 10);

    dim3 ggrid((N + 127) / 128, 4);
    int ablocks = (N + 3) / 4;

    // layer 0 (D=128)
    agg_kernel<2><<<ablocks, 256, 0, stream>>>(xb0, rowptr, colsrc, h, N);
    gemm_kernel<0, true,  false><<<ggrid, 256, 0, stream>>>(h, nullptr, nullptr, wt01, gb1[0], u,  N, 128);
    gemm_kernel<0, false, true ><<<ggrid, 256, 0, stream>>>(u, nullptr, nullptr, wt02, gb2[0], xb, N, 512);
    // layer 1
    agg_kernel<8><<<ablocks, 256, 0, stream>>>(xb, rowptr, colsrc, h, N);
    gemm_kernel<0, true,  false><<<ggrid, 256, 0, stream>>>(h, nullptr, nullptr, wt11, gb1[1], u,  N, 512);
    gemm_kernel<0, false, true ><<<ggrid, 256, 0, stream>>>(u, nullptr, nullptr, wt12, gb2[1], xb, N, 512);
    // layer 2
    agg_kernel<8><<<ablocks, 256, 0, stream>>>(xb, rowptr, colsrc, h, N);
    gemm_kernel<0, true,  false><<<ggrid, 256, 0, stream>>>(h, nullptr, nullptr, wt21, gb1[2], u,  N, 512);
    gemm_kernel<0, false, true ><<<ggrid, 256, 0, stream>>>(u, nullptr, nullptr, wt22, gb2[2], xb, N, 512);

    // prediction head
    constvec_kernel<<<1, 512, 0, stream>>>(xb, first_edge, t, tw1, tb1, tw2, tb2, pw1, pb1, cvec);
    dim3 hgrid((C + 127) / 128, 4);
    gemm_kernel<1, true, false><<<hgrid, 256, 0, stream>>>(nullptr, xb, cand, wtH, cvec, u, C, 1024);
    logits_kernel<<<(C + 3) / 4, 256, 0, stream>>>(u, pw2, pb2, (float*)d_out, C);
}

// Round 3
// 1479.497 us; speedup vs baseline: 1.2517x; 1.2517x over previous
//
#include <hip/hip_runtime.h>

typedef __bf16 bf16x2 __attribute__((ext_vector_type(2)));
typedef __bf16 bf16x4 __attribute__((ext_vector_type(4)));
typedef __bf16 bf16x8 __attribute__((ext_vector_type(8)));
typedef float f32x4 __attribute__((ext_vector_type(4)));

#define LDSTR 40  // LDS row stride in bf16 elems

// ---------------- CSR build ----------------
__global__ void hist_kernel(const int* __restrict__ dst, int* __restrict__ deg, int E) {
    int i = blockIdx.x * 256 + threadIdx.x;
    if (i < E) atomicAdd(&deg[dst[i]], 1);
}

__global__ __launch_bounds__(1024)
void scan_kernel(const int* __restrict__ deg, int* __restrict__ rowptr,
                 int* __restrict__ cursor, int n) {
    __shared__ int part[1024];
    int tid = threadIdx.x;
    int chunk = (n + 1023) >> 10;
    int beg = tid * chunk;
    int fin = min(beg + chunk, n);
    int s = 0;
    for (int i = beg; i < fin; i++) s += deg[i];
    part[tid] = s;
    __syncthreads();
    for (int off = 1; off < 1024; off <<= 1) {
        int v = (tid >= off) ? part[tid - off] : 0;
        __syncthreads();
        part[tid] += v;
        __syncthreads();
    }
    int run = (tid == 0) ? 0 : part[tid - 1];
    for (int i = beg; i < fin; i++) {
        rowptr[i] = run; cursor[i] = run; run += deg[i];
    }
    if (tid == 1023) rowptr[n] = run;
}

__global__ void scatter_kernel(const int* __restrict__ src, const int* __restrict__ dst,
                               int* __restrict__ cursor, int* __restrict__ colsrc, int E) {
    int i = blockIdx.x * 256 + threadIdx.x;
    if (i < E) {
        int p = atomicAdd(&cursor[dst[i]], 1);
        colsrc[p] = src[i];
    }
}

// ---------------- dtype convert / weight prep ----------------
__global__ void f32_to_bf16_kernel(const float* __restrict__ in, __bf16* __restrict__ out, int n4) {
    int i = blockIdx.x * 256 + threadIdx.x;
    if (i < n4) {
        float4 f = ((const float4*)in)[i];
        bf16x4 o;
        o[0] = (__bf16)f.x; o[1] = (__bf16)f.y; o[2] = (__bf16)f.z; o[3] = (__bf16)f.w;
        ((bf16x4*)out)[i] = o;
    }
}

// out[n*K+k] = bf16(in[k*512+n]); K = 1<<kbits (in is K x 512 row-major)
__global__ void wprep_kernel(const float* __restrict__ in, __bf16* __restrict__ out, int kbits) {
    int idx = blockIdx.x * 256 + threadIdx.x;
    int K = 1 << kbits;
    if (idx < (512 << kbits)) {
        int k = idx & (K - 1);
        int n = idx >> kbits;
        out[idx] = (__bf16)in[k * 512 + n];
    }
}

// ---------------- aggregation: h[i] = x[i] + sum_{j->i} x[j]  (wave per node, bf16 out) ----------------
template<int F>  // bf16 per lane; DIM = 64*F
__global__ __launch_bounds__(256)
void agg_kernel(const __bf16* __restrict__ xb, const int* __restrict__ rowptr,
                const int* __restrict__ colsrc, __bf16* __restrict__ h, int n) {
    const int node = blockIdx.x * 4 + (threadIdx.x >> 6);
    if (node >= n) return;
    const int lane = threadIdx.x & 63;
    const int DIM = F * 64;
    float acc[F];
    {
        const __bf16* p = xb + (size_t)node * DIM + lane * F;
        if constexpr (F == 8) {
            bf16x8 v = *(const bf16x8*)p;
            #pragma unroll
            for (int i = 0; i < 8; i++) acc[i] = (float)v[i];
        } else {
            bf16x2 v = *(const bf16x2*)p;
            acc[0] = (float)v[0]; acc[1] = (float)v[1];
        }
    }
    int e = rowptr[node], end = rowptr[node + 1];
    for (; e + 2 <= end; e += 2) {
        int s0 = colsrc[e], s1 = colsrc[e + 1];
        const __bf16* p0 = xb + (size_t)s0 * DIM + lane * F;
        const __bf16* p1 = xb + (size_t)s1 * DIM + lane * F;
        if constexpr (F == 8) {
            bf16x8 v0 = *(const bf16x8*)p0;
            bf16x8 v1 = *(const bf16x8*)p1;
            #pragma unroll
            for (int i = 0; i < 8; i++) acc[i] += (float)v0[i] + (float)v1[i];
        } else {
            bf16x2 v0 = *(const bf16x2*)p0;
            bf16x2 v1 = *(const bf16x2*)p1;
            acc[0] += (float)v0[0] + (float)v1[0];
            acc[1] += (float)v0[1] + (float)v1[1];
        }
    }
    if (e < end) {
        int s0 = colsrc[e];
        const __bf16* p0 = xb + (size_t)s0 * DIM + lane * F;
        if constexpr (F == 8) {
            bf16x8 v0 = *(const bf16x8*)p0;
            #pragma unroll
            for (int i = 0; i < 8; i++) acc[i] += (float)v0[i];
        } else {
            bf16x2 v0 = *(const bf16x2*)p0;
            acc[0] += (float)v0[0]; acc[1] += (float)v0[1];
        }
    }
    __bf16* out = h + (size_t)node * DIM + lane * F;
    if constexpr (F == 8) {
        bf16x8 o;
        #pragma unroll
        for (int i = 0; i < 8; i++) o[i] = (__bf16)acc[i];
        *(bf16x8*)out = o;
    } else {
        bf16x2 o; o[0] = (__bf16)acc[0]; o[1] = (__bf16)acc[1];
        *(bf16x2*)out = o;
    }
}

// ---------------- MFMA GEMM: out = epilogue(A @ Bt^T + bias), all-bf16 A path ----------------
// Tile: 64(M) x 256(N), 256 threads = 4 waves (waveN 0..3), each wave 64x64 via 4x4 mfma_16x16x32.
// grid = (ceil(M/64), 512/256=2). A re-read only 2x.
// AMODE 0: A bf16 row-major MxK. AMODE 1: A constructed from Xb gather via cand (K=1024).
template<int AMODE, bool RELU>
__global__ __launch_bounds__(256, 3)
void gemm_kernel(const __bf16* __restrict__ A, const __bf16* __restrict__ Xb,
                 const int* __restrict__ cand, const __bf16* __restrict__ Bt,
                 const float* __restrict__ bias, __bf16* __restrict__ Cout,
                 int M, int K) {
    __shared__ __bf16 sA[64 * LDSTR];
    __shared__ __bf16 sB[256 * LDSTR];

    const int tid = threadIdx.x;
    const int lane = tid & 63;
    const int waveN = tid >> 6;
    const int mlane = lane & 15;
    const int quad = lane >> 4;
    const int rowBase = blockIdx.x * 64;
    const int nBase = blockIdx.y * 256;

    const int ar = tid >> 2;        // A stage: 64 rows x 4 col-groups (8 bf16 each)
    const int ac = (tid & 3) << 3;
    const int br = tid >> 2;        // B stage: 64 rows/iter x 4 col-groups, 4 iters
    const int bc = (tid & 3) << 3;

    const f32x4 fzero = {0.f, 0.f, 0.f, 0.f};
    f32x4 acc[4][4];
    #pragma unroll
    for (int i = 0; i < 4; i++)
        #pragma unroll
        for (int j = 0; j < 4; j++) acc[i][j] = fzero;

    int uu = 0, vv = 0;
    const int grow = rowBase + ar;
    if (AMODE == 1 && grow < M) { uu = cand[2 * grow]; vv = cand[2 * grow + 1]; }

    for (int k0 = 0; k0 < K; k0 += 32) {
        __syncthreads();
        // ---- stage A ----
        {
            bf16x8 av = {};
            if (AMODE == 0) {
                if (grow < M) av = *(const bf16x8*)(A + (size_t)grow * K + k0 + ac);
            } else {
                if (grow < M) {
                    int k = k0 + ac;               // chunk of 8 never crosses the 512 boundary
                    int kk = k & 511;
                    bf16x8 xu = *(const bf16x8*)(Xb + (size_t)uu * 512 + kk);
                    bf16x8 xv = *(const bf16x8*)(Xb + (size_t)vv * 512 + kk);
                    if (k < 512) {
                        #pragma unroll
                        for (int q = 0; q < 8; q++) av[q] = (__bf16)((float)xu[q] + (float)xv[q]);
                    } else {
                        #pragma unroll
                        for (int q = 0; q < 8; q++) av[q] = (__bf16)fabsf((float)xu[q] - (float)xv[q]);
                    }
                }
            }
            *(bf16x8*)(sA + ar * LDSTR + ac) = av;
        }
        // ---- stage B ----
        #pragma unroll
        for (int i = 0; i < 4; i++) {
            int nn = br + i * 64;
            bf16x8 b = *(const bf16x8*)(Bt + (size_t)(nBase + nn) * K + k0 + bc);
            *(bf16x8*)(sB + nn * LDSTR + bc) = b;
        }
        __syncthreads();

        // ---- fragments + MFMA ----
        bf16x8 aF[4], bF[4];
        #pragma unroll
        for (int mt = 0; mt < 4; mt++)
            aF[mt] = *(const bf16x8*)(sA + (mt * 16 + mlane) * LDSTR + quad * 8);
        #pragma unroll
        for (int nt = 0; nt < 4; nt++)
            bF[nt] = *(const bf16x8*)(sB + (waveN * 64 + nt * 16 + mlane) * LDSTR + quad * 8);
        #pragma unroll
        for (int mt = 0; mt < 4; mt++)
            #pragma unroll
            for (int nt = 0; nt < 4; nt++)
                acc[mt][nt] = __builtin_amdgcn_mfma_f32_16x16x32_bf16(aF[mt], bF[nt], acc[mt][nt], 0, 0, 0);
    }

    // ---- epilogue: D col=lane&15, row=quad*4+r ----
    #pragma unroll
    for (int mt = 0; mt < 4; mt++) {
        #pragma unroll
        for (int nt = 0; nt < 4; nt++) {
            int col = nBase + waveN * 64 + nt * 16 + mlane;
            float bv = bias[col];
            #pragma unroll
            for (int r = 0; r < 4; r++) {
                int row = rowBase + mt * 16 + quad * 4 + r;
                if (row < M) {
                    float v = acc[mt][nt][r] + bv;
                    if (RELU) v = fmaxf(v, 0.f);
                    Cout[(size_t)row * 512 + col] = (__bf16)v;
                }
            }
        }
    }
}

// ---------------- head constant vector ----------------
__global__ __launch_bounds__(512)
void constvec_kernel(const __bf16* __restrict__ xb, const int* __restrict__ first_edge,
                     const float* __restrict__ t,
                     const float* __restrict__ tw1, const float* __restrict__ tb1,
                     const float* __restrict__ tw2, const float* __restrict__ tb2,
                     const float* __restrict__ pw1, const float* __restrict__ pb1,
                     float* __restrict__ cvec) {
    __shared__ float z1[512];
    __shared__ float te[512];
    __shared__ float ff[1024];
    int tid = threadIdx.x;
    float tv = t[0];
    z1[tid] = fmaxf(tv * tw1[tid] + tb1[tid], 0.f);
    int u = first_edge[0], v = first_edge[1];
    float xu = (float)xb[(size_t)u * 512 + tid];
    float xv = (float)xb[(size_t)v * 512 + tid];
    ff[tid] = xu + xv;
    ff[512 + tid] = fabsf(xu - xv);
    __syncthreads();
    float s = tb2[tid];
    for (int j = 0; j < 512; j++) s += z1[j] * tw2[j * 512 + tid];
    te[tid] = s;
    __syncthreads();
    float c = pb1[tid];
    for (int k = 0; k < 1024; k++) c += ff[k] * pw1[k * 512 + tid];
    for (int j = 0; j < 512; j++) c += te[j] * pw1[(2048 + j) * 512 + tid];
    cvec[tid] = c;
}

// ---------------- final dot: logits[c] = Z[c,:] . w2 + b2  (Z bf16) ----------------
__global__ __launch_bounds__(256)
void logits_kernel(const __bf16* __restrict__ Z, const float* __restrict__ w2,
                   const float* __restrict__ b2, float* __restrict__ out, int C) {
    int c = blockIdx.x * 4 + (threadIdx.x >> 6);
    if (c >= C) return;
    int lane = threadIdx.x & 63;
    bf16x8 z = *(const bf16x8*)(Z + (size_t)c * 512 + lane * 8);
    const float4* w = (const float4*)(w2 + lane * 8);
    float4 w0 = w[0], w1 = w[1];
    float s = (float)z[0] * w0.x + (float)z[1] * w0.y + (float)z[2] * w0.z + (float)z[3] * w0.w
            + (float)z[4] * w1.x + (float)z[5] * w1.y + (float)z[6] * w1.z + (float)z[7] * w1.w;
    #pragma unroll
    for (int off = 32; off > 0; off >>= 1) s += __shfl_down(s, off);
    if (lane == 0) out[c] = s + b2[0];
}

extern "C" void kernel_launch(void* const* d_in, const int* in_sizes, int n_in,
                              void* d_out, int out_size, void* d_ws, size_t ws_size,
                              hipStream_t stream) {
    (void)n_in; (void)out_size; (void)ws_size;
    const float* x          = (const float*)d_in[0];
    const int*   edge_index = (const int*)d_in[1];
    const int*   first_edge = (const int*)d_in[2];
    const int*   cand       = (const int*)d_in[3];
    const float* t          = (const float*)d_in[4];
    const float* gw1[3] = {(const float*)d_in[5], (const float*)d_in[9],  (const float*)d_in[13]};
    const float* gb1[3] = {(const float*)d_in[6], (const float*)d_in[10], (const float*)d_in[14]};
    const float* gw2[3] = {(const float*)d_in[7], (const float*)d_in[11], (const float*)d_in[15]};
    const float* gb2[3] = {(const float*)d_in[8], (const float*)d_in[12], (const float*)d_in[16]};
    const float* pw1 = (const float*)d_in[17];
    const float* pb1 = (const float*)d_in[18];
    const float* pw2 = (const float*)d_in[19];
    const float* pb2 = (const float*)d_in[20];
    const float* tw1 = (const float*)d_in[21];
    const float* tb1 = (const float*)d_in[22];
    const float* tw2 = (const float*)d_in[23];
    const float* tb2 = (const float*)d_in[24];

    const int N = in_sizes[0] / 128;   // 50000
    const int E = in_sizes[1] / 2;     // 1600000
    const int C = in_sizes[3] / 2;     // 50000

    char* p = (char*)d_ws;
    auto alloc = [&](size_t bytes) -> void* {
        void* r = (void*)p;
        p += (bytes + 255) & ~(size_t)255;
        return r;
    };
    __bf16* h    = (__bf16*)alloc((size_t)N * 512 * 2);
    __bf16* u    = (__bf16*)alloc((size_t)N * 512 * 2);  // also aliases xb0 pre-L0, and Z for head
    __bf16* xb   = (__bf16*)alloc((size_t)N * 512 * 2);
    __bf16* wt01 = (__bf16*)alloc((size_t)512 * 128 * 2);
    __bf16* wt02 = (__bf16*)alloc((size_t)512 * 512 * 2);
    __bf16* wt11 = (__bf16*)alloc((size_t)512 * 512 * 2);
    __bf16* wt12 = (__bf16*)alloc((size_t)512 * 512 * 2);
    __bf16* wt21 = (__bf16*)alloc((size_t)512 * 512 * 2);
    __bf16* wt22 = (__bf16*)alloc((size_t)512 * 512 * 2);
    __bf16* wtH  = (__bf16*)alloc((size_t)512 * 1024 * 2);
    int* rowptr = (int*)alloc((size_t)(N + 1) * 4);
    int* deg    = (int*)alloc((size_t)N * 4);
    int* cursor = (int*)alloc((size_t)N * 4);
    int* colsrc = (int*)alloc((size_t)E * 4);
    float* cvec = (float*)alloc(512 * 4);
    __bf16* xb0 = (__bf16*)u;   // alias: xb0 dead before u is first written (L0 gemm1)

    const int* src = edge_index;
    const int* dst = edge_index + E;

    // CSR build
    hipMemsetAsync(deg, 0, (size_t)N * 4, stream);
    int eb = (E + 255) / 256;
    hist_kernel<<<eb, 256, 0, stream>>>(dst, deg, E);
    scan_kernel<<<1, 1024, 0, stream>>>(deg, rowptr, cursor, N);
    scatter_kernel<<<eb, 256, 0, stream>>>(src, dst, cursor, colsrc, E);

    // input + weight prep
    f32_to_bf16_kernel<<<((N * 128 / 4) + 255) / 256, 256, 0, stream>>>(x, xb0, N * 128 / 4);
    wprep_kernel<<<((512 << 7)  + 255) / 256, 256, 0, stream>>>(gw1[0], wt01, 7);
    wprep_kernel<<<((512 << 9)  + 255) / 256, 256, 0, stream>>>(gw2[0], wt02, 9);
    wprep_kernel<<<((512 << 9)  + 255) / 256, 256, 0, stream>>>(gw1[1], wt11, 9);
    wprep_kernel<<<((512 << 9)  + 255) / 256, 256, 0, stream>>>(gw2[1], wt12, 9);
    wprep_kernel<<<((512 << 9)  + 255) / 256, 256, 0, stream>>>(gw1[2], wt21, 9);
    wprep_kernel<<<((512 << 9)  + 255) / 256, 256, 0, stream>>>(gw2[2], wt22, 9);
    wprep_kernel<<<((512 << 10) + 255) / 256, 256, 0, stream>>>(pw1 + (size_t)1024 * 512, wtH, 10);

    dim3 ggrid((N + 63) / 64, 2);
    int ablocks = (N + 3) / 4;

    // layer 0 (D=128)
    agg_kernel<2><<<ablocks, 256, 0, stream>>>(xb0, rowptr, colsrc, h, N);
    gemm_kernel<0, true ><<<ggrid, 256, 0, stream>>>(h, nullptr, nullptr, wt01, gb1[0], u,  N, 128);
    gemm_kernel<0, false><<<ggrid, 256, 0, stream>>>(u, nullptr, nullptr, wt02, gb2[0], xb, N, 512);
    // layer 1
    agg_kernel<8><<<ablocks, 256, 0, stream>>>(xb, rowptr, colsrc, h, N);
    gemm_kernel<0, true ><<<ggrid, 256, 0, stream>>>(h, nullptr, nullptr, wt11, gb1[1], u,  N, 512);
    gemm_kernel<0, false><<<ggrid, 256, 0, stream>>>(u, nullptr, nullptr, wt12, gb2[1], xb, N, 512);
    // layer 2
    agg_kernel<8><<<ablocks, 256, 0, stream>>>(xb, rowptr, colsrc, h, N);
    gemm_kernel<0, true ><<<ggrid, 256, 0, stream>>>(h, nullptr, nullptr, wt21, gb1[2], u,  N, 512);
    gemm_kernel<0, false><<<ggrid, 256, 0, stream>>>(u, nullptr, nullptr, wt22, gb2[2], xb, N, 512);

    // prediction head
    constvec_kernel<<<1, 512, 0, stream>>>(xb, first_edge, t, tw1, tb1, tw2, tb2, pw1, pb1, cvec);
    dim3 hgrid((C + 63) / 64, 2);
    gemm_kernel<1, true><<<hgrid, 256, 0, stream>>>(nullptr, xb, cand, wtH, cvec, u, C, 1024);
    logits_kernel<<<(C + 3) / 4, 256, 0, stream>>>(u, pw2, pb2, (float*)d_out, C);
}